// Round 2
// baseline (895.112 us; speedup 1.0000x reference)
//
#include <hip/hip_runtime.h>
#include <math.h>

#define NN 50000
#define NE 800000
#define MUL 32
#define NATTR 8
#define NEMB 8
#define HID 8
#define NPATH 5

static __device__ __forceinline__ float sigmoidf_(float v) {
    return 1.0f / (1.0f + __expf(-v));
}

// norm constants
#define INV_SQRT_MUL   0.17677669529663687f   /* 1/sqrt(32) */
#define INV_SQRT_NEMB  0.35355339059327373f   /* 1/sqrt(8)  */
#define INV_SQRT_HID   0.35355339059327373f   /* 1/sqrt(8)  */
#define INV3C          0.5773502691896258f    /* 1/sqrt(3)  */
#define INV2C          0.7071067811865476f    /* 1/sqrt(2)  */
#define INV_NEIGH      0.25f                  /* 1/sqrt(16) */
#define INV_SQRT_2MUL  0.125f                 /* 1/sqrt(64) */
#define INV_SQRT_3MUL  0.10206207261596575f   /* 1/sqrt(96) */
#define NSC            0.0625f                /* 1/sqrt(32*8) */

// ---------------------------------------------------------------------------
// K1: per-node linear_1 (-> x[N,128]) + self-connection (-> out[N,128])
// block = 128 threads (one per output channel), grid = N
// x layout: [0..31]=x_s[v], [32+u*3+c]=x_v[u][c]
// ---------------------------------------------------------------------------
__global__ __launch_bounds__(128) void k_node(
    const float* __restrict__ node_s, const float* __restrict__ node_v,
    const float* __restrict__ attrs,
    const float* __restrict__ W1_s, const float* __restrict__ W1_v,
    const float* __restrict__ Wsc_s, const float* __restrict__ Wsc_v,
    float* __restrict__ x, float* __restrict__ out)
{
    __shared__ float nd[136];    // node_s(32) | node_v(96) | attrs(8)
    __shared__ float gv[1024];   // g_v[u*32+vch] = sum_a attr[a]*Wsc_v[u,a,vch]
    const int n = blockIdx.x;
    const int t = threadIdx.x;

    // stage node data: 128 threads cover slots 0..127; threads 0..7 also
    // load the 8 attrs (slots 128..135).  [R1 fix: previous code guarded
    // with t<136 but the block only has 128 threads -> attrs never loaded]
    if (t < 32)       nd[t] = node_s[n * 32 + t];
    else              nd[t] = node_v[n * 96 + (t - 32)];
    if (t < 8)        nd[128 + t] = attrs[n * 8 + t];
    __syncthreads();

    float at[8];
#pragma unroll
    for (int a = 0; a < 8; ++a) at[a] = nd[128 + a];

    // build g_v (1024 entries, 8 per thread)
#pragma unroll
    for (int r = 0; r < 8; ++r) {
        int idx = t + 128 * r;
        int u = idx >> 5, vch = idx & 31;
        float g = 0.f;
#pragma unroll
        for (int a = 0; a < 8; ++a) g += at[a] * Wsc_v[(u * 8 + a) * 32 + vch];
        gv[idx] = g;
    }
    __syncthreads();

    float xa = 0.f, sc = 0.f;
    if (t < 32) {
#pragma unroll
        for (int u = 0; u < 32; ++u) xa += nd[u] * W1_s[u * 32 + t];
#pragma unroll
        for (int u = 0; u < 32; ++u) {
            float inner = 0.f;
#pragma unroll
            for (int a = 0; a < 8; ++a) inner += at[a] * Wsc_s[(u * 8 + a) * 32 + t];
            sc += nd[u] * inner;
        }
    } else {
        int q = t - 32;
        int vch = q / 3, c = q - 3 * vch;
#pragma unroll
        for (int u = 0; u < 32; ++u) xa += nd[32 + u * 3 + c] * W1_v[u * 32 + vch];
#pragma unroll
        for (int u = 0; u < 32; ++u) sc += nd[32 + u * 3 + c] * gv[(u << 5) + vch];
    }
    x[n * 128 + t]   = xa * INV_SQRT_MUL;
    out[n * 128 + t] = sc * NSC;   // message part added later by k_gather
}

// ---------------------------------------------------------------------------
// K2: per-edge radial-MLP hidden layer h[E,8] + dst histogram
// ---------------------------------------------------------------------------
__global__ __launch_bounds__(256) void k_edge_pre(
    const float* __restrict__ edge_emb, const float* __restrict__ Wm1,
    const int* __restrict__ edge_dst,
    float* __restrict__ hbuf, int* __restrict__ counts)
{
    int e = blockIdx.x * 256 + threadIdx.x;
    if (e >= NE) return;
    const float4* p = (const float4*)(edge_emb + e * 8);
    float4 a = p[0], b = p[1];
    float emb[8] = {a.x, a.y, a.z, a.w, b.x, b.y, b.z, b.w};
    float h[8];
#pragma unroll
    for (int j = 0; j < 8; ++j) {
        float s = 0.f;
#pragma unroll
        for (int k = 0; k < 8; ++k) s += emb[k] * Wm1[k * 8 + j];
        s *= INV_SQRT_NEMB;
        h[j] = s * sigmoidf_(s);   // silu
    }
    float4* o = (float4*)(hbuf + e * 8);
    o[0] = make_float4(h[0], h[1], h[2], h[3]);
    o[1] = make_float4(h[4], h[5], h[6], h[7]);
    atomicAdd(&counts[edge_dst[e]], 1);
}

// ---------------------------------------------------------------------------
// K3: exclusive scan of counts -> offsets[N+1], cursor[N]. One block of 1024.
// ---------------------------------------------------------------------------
__global__ __launch_bounds__(1024) void k_scan(
    const int* __restrict__ counts, int* __restrict__ offsets,
    int* __restrict__ cursor)
{
    __shared__ int part[1024];
    const int t = threadIdx.x;
    const int CH = (NN + 1023) / 1024;  // 49
    int lo = t * CH, hi = lo + CH;
    if (hi > NN) hi = NN;
    if (lo > NN) lo = NN;
    int s = 0;
    for (int i = lo; i < hi; ++i) s += counts[i];
    part[t] = s;
    __syncthreads();
    for (int off = 1; off < 1024; off <<= 1) {
        int v = (t >= off) ? part[t - off] : 0;
        __syncthreads();
        part[t] += v;
        __syncthreads();
    }
    int run = (t == 0) ? 0 : part[t - 1];
    if (t == 0) offsets[0] = 0;
    for (int i = lo; i < hi; ++i) {
        cursor[i] = run;
        run += counts[i];
        offsets[i + 1] = run;
    }
}

// ---------------------------------------------------------------------------
// K4: bucket edge ids by dst
// ---------------------------------------------------------------------------
__global__ __launch_bounds__(256) void k_scatter(
    const int* __restrict__ edge_dst, int* __restrict__ cursor,
    int* __restrict__ csr)
{
    int e = blockIdx.x * 256 + threadIdx.x;
    if (e >= NE) return;
    int pos = atomicAdd(&cursor[edge_dst[e]], 1);
    csr[pos] = e;
}

// ---------------------------------------------------------------------------
// K5: one wave per node: loop incoming edges, build 352-float message acc
// distributed across lanes, then fold W2 and += into out.
// msg layout: [0..31]=p1, [32..63]=p2, [64+uu*3+c] uu=path*32+u for p3,p4,p5
// ---------------------------------------------------------------------------
__global__ __launch_bounds__(64) void k_gather(
    const float* __restrict__ x, const float* __restrict__ hbuf,
    const float* __restrict__ edge_sh0, const float* __restrict__ edge_sh1,
    const int* __restrict__ edge_src,
    const float* __restrict__ Wm2, const float* __restrict__ W2_s,
    const float* __restrict__ W2_v,
    const int* __restrict__ offsets, const int* __restrict__ csr,
    float* __restrict__ out)
{
    __shared__ float xb[128];
    __shared__ float wb[160];
    __shared__ float msg[352];
    const int n = blockIdx.x;
    const int lane = threadIdx.x;

    // loop-invariant slot decomposition: slot k holds msg[lane + 64k]
    int s_path[6], s_u[6], s_c[6];
#pragma unroll
    for (int k = 0; k < 6; ++k) {
        int m = lane + 64 * k;
        if (m < 32)       { s_path[k] = 0; s_u[k] = m;      s_c[k] = 0; }
        else if (m < 64)  { s_path[k] = 1; s_u[k] = m - 32; s_c[k] = 0; }
        else if (m < 352) {
            int tt = m - 64;
            int uu = tt / 3;
            s_path[k] = 2 + (uu >> 5);
            s_u[k] = uu & 31;
            s_c[k] = tt - 3 * uu;
        } else            { s_path[k] = -1; s_u[k] = 0; s_c[k] = 0; }
    }
    float acc[6] = {0.f, 0.f, 0.f, 0.f, 0.f, 0.f};

    const int beg = offsets[n];
    const int end = offsets[n + 1];

    for (int j = beg; j < end; ++j) {
        const int e = csr[j];
        const int src = edge_src[e];
        const float sh0 = edge_sh0[e];
        const float sx = edge_sh1[3 * e];
        const float sy = edge_sh1[3 * e + 1];
        const float sz = edge_sh1[3 * e + 2];
        float hh[8];
        {
            const float4* hp = (const float4*)(hbuf + 8 * e);
            float4 h0 = hp[0], h1 = hp[1];
            hh[0] = h0.x; hh[1] = h0.y; hh[2] = h0.z; hh[3] = h0.w;
            hh[4] = h1.x; hh[5] = h1.y; hh[6] = h1.z; hh[7] = h1.w;
        }
        __syncthreads();  // prior iteration's LDS reads complete
        {
            const float2* xp = (const float2*)(x + 128 * src);
            float2 tv = xp[lane];
            xb[2 * lane]     = tv.x;
            xb[2 * lane + 1] = tv.y;
        }
        // w[m] = (h . Wm2[:,m]) / sqrt(HID), m = path*32+u
#pragma unroll
        for (int r = 0; r < 3; ++r) {
            int m = lane + 64 * r;
            if (m < 160) {
                float s = 0.f;
#pragma unroll
                for (int q = 0; q < 8; ++q) s += hh[q] * Wm2[q * 160 + m];
                wb[m] = s * INV_SQRT_HID;
            }
        }
        __syncthreads();
#pragma unroll
        for (int k = 0; k < 6; ++k) {
            const int p = s_path[k], u = s_u[k], c = s_c[k];
            if (p == 0) {
                acc[k] += wb[u] * xb[u] * sh0;
            } else if (p == 1) {
                int vb = 32 + 3 * u;
                float dot = xb[vb] * sx + xb[vb + 1] * sy + xb[vb + 2] * sz;
                acc[k] += wb[32 + u] * dot * INV3C;
            } else if (p == 2) {
                float s1 = (c == 0) ? sx : ((c == 1) ? sy : sz);
                acc[k] += wb[64 + u] * xb[u] * s1;
            } else if (p == 3) {
                acc[k] += wb[96 + u] * xb[32 + 3 * u + c] * sh0;
            } else if (p == 4) {
                int vb = 32 + 3 * u;
                int c1 = (c == 2) ? 0 : c + 1;
                int c2 = (c == 0) ? 2 : c - 1;
                float sA = (c1 == 0) ? sx : ((c1 == 1) ? sy : sz);
                float sB = (c2 == 0) ? sx : ((c2 == 1) ? sy : sz);
                float cr = xb[vb + c1] * sB - xb[vb + c2] * sA;
                acc[k] += wb[128 + u] * cr * INV2C;
            }
        }
    }

    __syncthreads();
#pragma unroll
    for (int k = 0; k < 6; ++k) {
        int m = lane + 64 * k;
        if (m < 352) msg[m] = acc[k] * INV_NEIGH;
    }
    __syncthreads();

    // fold linear_2, add to self-connection already in out
#pragma unroll
    for (int oo = 0; oo < 2; ++oo) {
        int o = oo * 64 + lane;
        float r;
        if (o < 32) {
            float s = 0.f;
#pragma unroll
            for (int u = 0; u < 64; ++u) s += msg[u] * W2_s[u * 32 + o];
            r = s * INV_SQRT_2MUL;
        } else {
            int q = o - 32;
            int vch = q / 3, c = q - 3 * vch;
            float s = 0.f;
#pragma unroll
            for (int uu = 0; uu < 96; ++uu) s += msg[64 + uu * 3 + c] * W2_v[uu * 32 + vch];
            r = s * INV_SQRT_3MUL;
        }
        out[128 * n + o] += r;
    }
}

// ---------------------------------------------------------------------------
extern "C" void kernel_launch(void* const* d_in, const int* in_sizes, int n_in,
                              void* d_out, int out_size, void* d_ws, size_t ws_size,
                              hipStream_t stream) {
    const float* node_s   = (const float*)d_in[0];
    const float* node_v   = (const float*)d_in[1];
    const float* attrs    = (const float*)d_in[2];
    const float* edge_emb = (const float*)d_in[3];
    const float* edge_sh0 = (const float*)d_in[4];
    const float* edge_sh1 = (const float*)d_in[5];
    const float* W1_s     = (const float*)d_in[6];
    const float* W1_v     = (const float*)d_in[7];
    const float* Wm1      = (const float*)d_in[8];
    const float* Wm2      = (const float*)d_in[9];
    const float* W2_s     = (const float*)d_in[10];
    const float* W2_v     = (const float*)d_in[11];
    const float* Wsc_s    = (const float*)d_in[12];
    const float* Wsc_v    = (const float*)d_in[13];
    const int*   edge_src = (const int*)d_in[14];
    const int*   edge_dst = (const int*)d_in[15];
    float* out = (float*)d_out;

    // workspace layout
    float* x    = (float*)d_ws;                // N*128
    float* hbuf = x + (size_t)NN * 128;        // E*8
    int*   counts  = (int*)(hbuf + (size_t)NE * 8);  // N
    int*   offsets = counts + NN;              // N+1
    int*   cursor  = offsets + NN + 1;         // N
    int*   csr     = cursor + NN;              // E

    hipMemsetAsync(counts, 0, NN * sizeof(int), stream);

    k_node<<<NN, 128, 0, stream>>>(node_s, node_v, attrs, W1_s, W1_v,
                                   Wsc_s, Wsc_v, x, out);
    k_edge_pre<<<(NE + 255) / 256, 256, 0, stream>>>(edge_emb, Wm1, edge_dst,
                                                     hbuf, counts);
    k_scan<<<1, 1024, 0, stream>>>(counts, offsets, cursor);
    k_scatter<<<(NE + 255) / 256, 256, 0, stream>>>(edge_dst, cursor, csr);
    k_gather<<<NN, 64, 0, stream>>>(x, hbuf, edge_sh0, edge_sh1, edge_src,
                                    Wm2, W2_s, W2_v, offsets, csr, out);
}